// Round 2
// baseline (28706.323 us; speedup 1.0000x reference)
//
#include <hip/hip_runtime.h>
#include <hip/hip_bf16.h>
#include <math.h>

typedef __hip_bfloat16 bf16;

// ---------- dtype-adaptive load/store (bf=1 -> bf16, bf=0 -> fp32) ----------
__device__ __forceinline__ float ldf(const void* p, size_t i, int bf) {
    if (bf) return __bfloat162float(((const bf16*)p)[i]);
    return ((const float*)p)[i];
}
__device__ __forceinline__ void stf(void* p, size_t i, int bf, float v) {
    if (bf) ((bf16*)p)[i] = __float2bfloat16(v);
    else    ((float*)p)[i] = v;
}

// ---------- dtype detector: vote on exponent-byte signature of fp1_p2 ----------
__global__ void k_detect(const void* __restrict__ probe, int* __restrict__ flag) {
    if (threadIdx.x == 0 && blockIdx.x == 0) {
        const unsigned int* w = (const unsigned int*)probe;
        int hits = 0;
        for (int i = 0; i < 256; ++i) {
            unsigned int hb = (w[i] >> 8) & 0x7Fu;   // bf16: exp[7:1] of low element
            if (hb >= 0x3Bu && hb <= 0x40u) ++hits;  // N(0,1) exponent band
        }
        *flag = (hits >= 128) ? 1 : 0;               // 1 = bf16, 0 = fp32
    }
}

// ---------- stitch index map (derived from the reference reshape chain) ----------
__device__ __forceinline__ void stitch_map(int y, int x, int s, int nh, int nw,
                                           int& n, int& e)
{
    int px = x % s;
    int d0 = x / s;
    int M  = d0 * (nh * s) + y;
    int py = M / (nw * nh);
    int rem = M - py * (nw * nh);
    int iw = rem / nh;
    int ih = rem - iw * nh;
    n = ih * nw + iw;
    e = py * s + px;
}

// ---------- patchify (+ optional align-corners bilinear up-resize) ----------
__global__ void k_patchify(const void* __restrict__ fp1, const void* __restrict__ fp2,
                           float* __restrict__ qb, float* __restrict__ pb,
                           const int* __restrict__ dflag,
                           int bc0, int chunk, int N, int E, int s, int nh, int nw,
                           int h_, int w_, int h, int w, int resize)
{
    int bf = *dflag;
    int idx = blockIdx.x * blockDim.x + threadIdx.x;
    int total = chunk * N * E;
    if (idx >= total) return;
    int e = idx % E; int t = idx / E;
    int n = t % N;   int i = t / N;
    int ih = n / nw, iw = n - ih * nw;
    int py = e / s,  px = e - py * s;
    int Y = ih * s + py, X = iw * s + px;
    size_t base = (size_t)(bc0 + i) * h_ * w_;
    float v1, v2;
    if (!resize) {
        size_t off = base + (size_t)Y * w_ + X;
        v1 = ldf(fp1, off, bf); v2 = ldf(fp2, off, bf);
    } else {
        float fy = (float)Y * ((float)(h_ - 1) / (float)(h - 1));
        float fx = (float)X * ((float)(w_ - 1) / (float)(w - 1));
        int y0 = (int)floorf(fy); int x0 = (int)floorf(fx);
        float wy = fy - (float)y0, wx = fx - (float)x0;
        int y1 = min(y0 + 1, h_ - 1), x1 = min(x0 + 1, w_ - 1);
        size_t r0 = base + (size_t)y0 * w_, r1 = base + (size_t)y1 * w_;
        {
            float a00 = ldf(fp1, r0 + x0, bf), a01 = ldf(fp1, r0 + x1, bf);
            float a10 = ldf(fp1, r1 + x0, bf), a11 = ldf(fp1, r1 + x1, bf);
            v1 = (a00 * (1.f - wy) + a10 * wy) * (1.f - wx)
               + (a01 * (1.f - wy) + a11 * wy) * wx;
        }
        {
            float a00 = ldf(fp2, r0 + x0, bf), a01 = ldf(fp2, r0 + x1, bf);
            float a10 = ldf(fp2, r1 + x0, bf), a11 = ldf(fp2, r1 + x1, bf);
            v2 = (a00 * (1.f - wy) + a10 * wy) * (1.f - wx)
               + (a01 * (1.f - wy) + a11 * wy) * wx;
        }
    }
    qb[idx] = v1;
    pb[idx] = v2;
}

// ---------- fused Q,K,V projection: block = E threads, R rows per block ----------
template<int R>
__global__ void k_qkv(const float* __restrict__ qb, const float* __restrict__ pb,
                      float* __restrict__ Q, float* __restrict__ K, float* __restrict__ V,
                      const void* __restrict__ qw, const void* __restrict__ kw,
                      const void* __restrict__ vw, const void* __restrict__ inb,
                      const int* __restrict__ dflag, int E)
{
    int bf = *dflag;
    int e = threadIdx.x;                 // [0, E)
    long row0 = (long)blockIdx.x * R;
    extern __shared__ float sm[];        // transposed: sq[f*R+r], sp[f*R+r]
    float* sq = sm;
    float* sp = sm + (size_t)E * R;
    for (int r = 0; r < R; ++r) {
        sq[(size_t)e * R + r] = qb[(row0 + r) * (size_t)E + e];
        sp[(size_t)e * R + r] = pb[(row0 + r) * (size_t)E + e];
    }
    __syncthreads();
    float aQ[R], aK[R], aV[R];
    float biQ = ldf(inb, e, bf), biK = ldf(inb, E + e, bf), biV = ldf(inb, 2 * E + e, bf);
#pragma unroll
    for (int r = 0; r < R; ++r) { aQ[r] = biQ; aK[r] = biK; aV[r] = biV; }
#pragma unroll 2
    for (int f = 0; f < E; ++f) {
        float wq  = ldf(qw, (size_t)e * E + f, bf);
        float wk1 = ldf(kw, (size_t)e * 2 * E + f, bf);
        float wk2 = ldf(kw, (size_t)e * 2 * E + E + f, bf);
        float wv1 = ldf(vw, (size_t)e * 2 * E + f, bf);
        float wv2 = ldf(vw, (size_t)e * 2 * E + E + f, bf);
#pragma unroll
        for (int r = 0; r < R; ++r) {
            float qf = sq[(size_t)f * R + r];
            float pf = sp[(size_t)f * R + r];
            aQ[r] += qf * wq;
            aK[r] += qf * wk1 + pf * wk2;
            aV[r] += qf * wv1 + pf * wv2;
        }
    }
#pragma unroll
    for (int r = 0; r < R; ++r) {
        size_t o = (row0 + r) * (size_t)E + e;
        Q[o] = aQ[r]; K[o] = aK[r]; V[o] = aV[r];
    }
}

// ---------- scores + softmax: block = N threads, R rows (R divides N) ----------
template<int R>
__global__ void k_scores(const float* __restrict__ Q, const float* __restrict__ K,
                         float* __restrict__ A, int N, int E, float scale)
{
    int m = threadIdx.x;                 // [0, N)
    long row0 = (long)blockIdx.x * R;
    int i = (int)(row0 / N);
    extern __shared__ float sm[];        // sq[E*R] transposed + sred[N]
    float* sq   = sm;
    float* sred = sm + (size_t)E * R;
    for (int r = 0; r < R; ++r)
        for (int e = m; e < E; e += N)
            sq[(size_t)e * R + r] = Q[(row0 + r) * (size_t)E + e];
    __syncthreads();
    const float* Kb = K + (size_t)i * N * E;
    float acc[R];
#pragma unroll
    for (int r = 0; r < R; ++r) acc[r] = 0.f;
#pragma unroll 2
    for (int e = 0; e < E; ++e) {
        float kv = Kb[(size_t)m * E + e];
#pragma unroll
        for (int r = 0; r < R; ++r) acc[r] += sq[(size_t)e * R + r] * kv;
    }
#pragma unroll
    for (int r = 0; r < R; ++r) acc[r] *= scale;
    for (int r = 0; r < R; ++r) {
        sred[m] = acc[r]; __syncthreads();
        for (int cnt = N; cnt > 1; ) {
            int half = (cnt + 1) >> 1;
            if (m < cnt - half) sred[m] = fmaxf(sred[m], sred[m + half]);
            __syncthreads();
            cnt = half;
        }
        float mx = sred[0]; __syncthreads();
        float ev = __expf(acc[r] - mx);
        sred[m] = ev; __syncthreads();
        for (int cnt = N; cnt > 1; ) {
            int half = (cnt + 1) >> 1;
            if (m < cnt - half) sred[m] += sred[m + half];
            __syncthreads();
            cnt = half;
        }
        float sum = sred[0]; __syncthreads();
        A[(row0 + r) * (size_t)N + m] = ev / sum;
    }
}

// ---------- O = A @ V: block = E threads, R rows (R divides N) ----------
template<int R>
__global__ void k_av(const float* __restrict__ A, const float* __restrict__ V,
                     float* __restrict__ O, int N, int E)
{
    int e = threadIdx.x;                 // [0, E)
    long row0 = (long)blockIdx.x * R;
    int i = (int)(row0 / N);
    extern __shared__ float sm[];        // sa[N*R] transposed
    for (int r = 0; r < R; ++r)
        for (int m = e; m < N; m += E)
            sm[(size_t)m * R + r] = A[(row0 + r) * (size_t)N + m];
    __syncthreads();
    const float* Vb = V + (size_t)i * N * E;
    float acc[R];
#pragma unroll
    for (int r = 0; r < R; ++r) acc[r] = 0.f;
#pragma unroll 2
    for (int m = 0; m < N; ++m) {
        float vv = Vb[(size_t)m * E + e];
#pragma unroll
        for (int r = 0; r < R; ++r) acc[r] += sm[(size_t)m * R + r] * vv;
    }
#pragma unroll
    for (int r = 0; r < R; ++r) O[(row0 + r) * (size_t)E + e] = acc[r];
}

// ---------- out-proj + LayerNorm: block = E threads, R rows ----------
template<int R>
__global__ void k_projln(const float* __restrict__ O, float* __restrict__ O2,
                         const void* __restrict__ ow, const void* __restrict__ ob,
                         const void* __restrict__ lng, const void* __restrict__ lnb,
                         const int* __restrict__ dflag, int E)
{
    int bf = *dflag;
    int e = threadIdx.x;
    long row0 = (long)blockIdx.x * R;
    extern __shared__ float sm[];        // so[E*R] transposed + sred[E]
    float* so   = sm;
    float* sred = sm + (size_t)E * R;
    for (int r = 0; r < R; ++r)
        so[(size_t)e * R + r] = O[(row0 + r) * (size_t)E + e];
    __syncthreads();
    float acc[R];
    float bo = ldf(ob, e, bf);
#pragma unroll
    for (int r = 0; r < R; ++r) acc[r] = bo;
#pragma unroll 2
    for (int f = 0; f < E; ++f) {
        float w = ldf(ow, (size_t)e * E + f, bf);
#pragma unroll
        for (int r = 0; r < R; ++r) acc[r] += so[(size_t)f * R + r] * w;
    }
    float g = ldf(lng, e, bf), bta = ldf(lnb, e, bf);
    for (int r = 0; r < R; ++r) {
        sred[e] = acc[r]; __syncthreads();
        for (int cnt = E; cnt > 1; ) {
            int half = (cnt + 1) >> 1;
            if (e < cnt - half) sred[e] += sred[e + half];
            __syncthreads();
            cnt = half;
        }
        float mu = sred[0] / (float)E; __syncthreads();
        float d = acc[r] - mu;
        sred[e] = d * d; __syncthreads();
        for (int cnt = E; cnt > 1; ) {
            int half = (cnt + 1) >> 1;
            if (e < cnt - half) sred[e] += sred[e + half];
            __syncthreads();
            cnt = half;
        }
        float var = sred[0] / (float)E; __syncthreads();
        O2[(row0 + r) * (size_t)E + e] = d * rsqrtf(var + 1e-5f) * g + bta;
    }
}

// ---------- final blend, no-resize levels ----------
__global__ void k_final(const float* __restrict__ O2,
                        const void* __restrict__ fp1, const void* __restrict__ fp2,
                        const void* __restrict__ logits, void* __restrict__ out,
                        const int* __restrict__ dflag, size_t obase,
                        int bc0, int chunk, int h, int w, int s, int nh, int nw,
                        int N, int E)
{
    int bf = *dflag;
    int idx = blockIdx.x * blockDim.x + threadIdx.x;
    int total = chunk * h * w;
    if (idx >= total) return;
    int x = idx % w; int t = idx / w;
    int y = t % h;   int i = t / h;
    int n, e;
    stitch_map(y, x, s, nh, nw, n, e);
    float fus = O2[((size_t)i * N + n) * E + e];
    float l0 = ldf(logits, 0, bf), l1 = ldf(logits, 1, bf), l2 = ldf(logits, 2, bf);
    float mx = fmaxf(l0, fmaxf(l1, l2));
    float e0 = __expf(l0 - mx), e1 = __expf(l1 - mx), e2 = __expf(l2 - mx);
    float inv = 1.f / (e0 + e1 + e2);
    size_t off = ((size_t)(bc0 + i) * h + y) * w + x;
    float v = ldf(fp1, off, bf) * (e0 * inv) + ldf(fp2, off, bf) * (e1 * inv)
            + fus * (e2 * inv);
    stf(out, obase + off, bf, v);
}

// ---------- stitch to full (rounded) grid, fp32 (p3 only) ----------
__global__ void k_stitch(const float* __restrict__ O2, float* __restrict__ st,
                         int chunk, int h, int w, int s, int nh, int nw, int N, int E)
{
    int idx = blockIdx.x * blockDim.x + threadIdx.x;
    int total = chunk * h * w;
    if (idx >= total) return;
    int x = idx % w; int t = idx / w;
    int y = t % h;   int i = t / h;
    int n, e;
    stitch_map(y, x, s, nh, nw, n, e);
    st[idx] = O2[((size_t)i * N + n) * E + e];
}

// ---------- down-resize (align corners) + blend (p3 only) ----------
__global__ void k_rblend(const float* __restrict__ st,
                         const void* __restrict__ fp1, const void* __restrict__ fp2,
                         const void* __restrict__ logits, void* __restrict__ out,
                         const int* __restrict__ dflag, size_t obase,
                         int bc0, int chunk, int h_, int w_, int h, int w)
{
    int bf = *dflag;
    int idx = blockIdx.x * blockDim.x + threadIdx.x;
    int total = chunk * h_ * w_;
    if (idx >= total) return;
    int x = idx % w_; int t = idx / w_;
    int y = t % h_;   int i = t / h_;
    float fy = (float)y * ((float)(h - 1) / (float)(h_ - 1));
    float fx = (float)x * ((float)(w - 1) / (float)(w_ - 1));
    int y0 = (int)floorf(fy); int x0 = (int)floorf(fx);
    float wy = fy - (float)y0, wx = fx - (float)x0;
    int y1 = min(y0 + 1, h - 1), x1 = min(x0 + 1, w - 1);
    size_t base = (size_t)i * h * w;
    float a00 = st[base + (size_t)y0 * w + x0], a01 = st[base + (size_t)y0 * w + x1];
    float a10 = st[base + (size_t)y1 * w + x0], a11 = st[base + (size_t)y1 * w + x1];
    float fus = (a00 * (1.f - wy) + a10 * wy) * (1.f - wx)
              + (a01 * (1.f - wy) + a11 * wy) * wx;
    float l0 = ldf(logits, 0, bf), l1 = ldf(logits, 1, bf), l2 = ldf(logits, 2, bf);
    float mx = fmaxf(l0, fmaxf(l1, l2));
    float e0 = __expf(l0 - mx), e1 = __expf(l1 - mx), e2 = __expf(l2 - mx);
    float inv = 1.f / (e0 + e1 + e2);
    size_t off = ((size_t)(bc0 + i) * h_ + y) * w_ + x;
    float v = ldf(fp1, off, bf) * (e0 * inv) + ldf(fp2, off, bf) * (e1 * inv)
            + fus * (e2 * inv);
    stf(out, obase + off, bf, v);
}

extern "C" void kernel_launch(void* const* d_in, const int* in_sizes, int n_in,
                              void* d_out, int out_size, void* d_ws, size_t ws_size,
                              hipStream_t stream)
{
    (void)in_sizes; (void)n_in; (void)out_size;
    const void* FP1[5]; const void* FP2[5];
    const void *QW[5], *KW[5], *VW[5], *INB[5], *OW[5], *OB[5], *LNG[5], *LNB[5];
    for (int l = 0; l < 5; ++l) {
        FP1[l] = d_in[l];
        FP2[l] = d_in[5 + l];
        int b = 10 + 8 * l;
        QW[l]  = d_in[b + 0];
        KW[l]  = d_in[b + 1];
        VW[l]  = d_in[b + 2];
        INB[l] = d_in[b + 3];
        OW[l]  = d_in[b + 4];
        OB[l]  = d_in[b + 5];
        LNG[l] = d_in[b + 6];
        LNB[l] = d_in[b + 7];
    }
    const void* logits = d_in[50];
    void* out = d_out;

    static const int HH[5] = {256, 128, 64, 32, 16};
    static const int SS[5] = {16, 12, 8, 4, 2};

    // dtype flag lives in the last 16 bytes of ws; 6 equal fp32 slots before it
    size_t flag_off = (ws_size - 16) & ~(size_t)15;
    int* dflag = (int*)((char*)d_ws + flag_off);
    size_t slot_bytes = ((flag_off) / 6) & ~(size_t)255;
    size_t slot_elems = slot_bytes / sizeof(float);
    float* slot[6];
    for (int i = 0; i < 6; ++i) slot[i] = (float*)((char*)d_ws + (size_t)i * slot_bytes);

    k_detect<<<1, 64, 0, stream>>>(FP1[0], dflag);

    size_t ooff = 0;
    for (int l = 0; l < 5; ++l) {
        int h_ = HH[l], w_ = HH[l], s = SS[l];
        int nh = (h_ % s == 0) ? (h_ / s) : (h_ / s + 1);
        int nw = nh;
        int h = nh * s, w = nw * s;
        int N = nh * nw, E = s * s;
        int resize = (h != h_) ? 1 : 0;
        int Rr = (l == 1) ? 11 : 8;     // must divide N (8|256, 11|121, 8|64)
        float scale = 1.0f / sqrtf((float)E);
        size_t maxNE = (size_t)N * (size_t)((E > N) ? E : N);

        int chunk = 512;
        size_t c = (maxNE > 0) ? (slot_elems / maxNE) : 0;
        if (c < 512) { int p = 1; while ((size_t)(p << 1) <= c) p <<= 1; chunk = p; }
        int nchunks = 512 / chunk;

        for (int cidx = 0; cidx < nchunks; ++cidx) {
            int bc0 = cidx * chunk;
            int rows = chunk * N;
            int blocksR = rows / Rr;
            // 1) patchify
            {
                int tot = chunk * N * E, tpb = 256, g = (tot + tpb - 1) / tpb;
                k_patchify<<<g, tpb, 0, stream>>>(FP1[l], FP2[l], slot[0], slot[1],
                                                  dflag, bc0, chunk, N, E, s, nh, nw,
                                                  h_, w_, h, w, resize);
            }
            // 2) QKV
            {
                size_t sh = (size_t)2 * Rr * E * sizeof(float);
                if (Rr == 8)
                    k_qkv<8><<<blocksR, E, sh, stream>>>(slot[0], slot[1], slot[2], slot[3], slot[4],
                                                         QW[l], KW[l], VW[l], INB[l], dflag, E);
                else
                    k_qkv<11><<<blocksR, E, sh, stream>>>(slot[0], slot[1], slot[2], slot[3], slot[4],
                                                          QW[l], KW[l], VW[l], INB[l], dflag, E);
            }
            // 3) scores + softmax
            {
                size_t sh = ((size_t)Rr * E + N) * sizeof(float);
                if (Rr == 8)
                    k_scores<8><<<blocksR, N, sh, stream>>>(slot[2], slot[3], slot[5], N, E, scale);
                else
                    k_scores<11><<<blocksR, N, sh, stream>>>(slot[2], slot[3], slot[5], N, E, scale);
            }
            // 4) O = A @ V
            {
                size_t sh = (size_t)Rr * N * sizeof(float);
                if (Rr == 8)
                    k_av<8><<<blocksR, E, sh, stream>>>(slot[5], slot[4], slot[0], N, E);
                else
                    k_av<11><<<blocksR, E, sh, stream>>>(slot[5], slot[4], slot[0], N, E);
            }
            // 5) out-proj + LN
            {
                size_t sh = ((size_t)Rr * E + E) * sizeof(float);
                if (Rr == 8)
                    k_projln<8><<<blocksR, E, sh, stream>>>(slot[0], slot[1],
                                                            OW[l], OB[l], LNG[l], LNB[l], dflag, E);
                else
                    k_projln<11><<<blocksR, E, sh, stream>>>(slot[0], slot[1],
                                                             OW[l], OB[l], LNG[l], LNB[l], dflag, E);
            }
            // 6) stitch (+resize) + blend
            if (!resize) {
                int tot = chunk * h * w, tpb = 256, g = (tot + tpb - 1) / tpb;
                k_final<<<g, tpb, 0, stream>>>(slot[1], FP1[l], FP2[l], logits, out,
                                               dflag, ooff, bc0, chunk, h, w, s, nh, nw, N, E);
            } else {
                int tot = chunk * h * w, tpb = 256, g = (tot + tpb - 1) / tpb;
                k_stitch<<<g, tpb, 0, stream>>>(slot[1], slot[2], chunk, h, w, s, nh, nw, N, E);
                int tot2 = chunk * h_ * w_, g2 = (tot2 + tpb - 1) / tpb;
                k_rblend<<<g2, tpb, 0, stream>>>(slot[2], FP1[l], FP2[l], logits, out,
                                                 dflag, ooff, bc0, chunk, h_, w_, h, w);
            }
        }
        ooff += (size_t)512 * h_ * w_;
    }
}